// Round 1
// baseline (353.260 us; speedup 1.0000x reference)
//
#include <hip/hip_runtime.h>

typedef short s8v __attribute__((ext_vector_type(8)));
typedef float f4v __attribute__((ext_vector_type(4)));

#define LQ 1568
#define LK 1568
#define NH 12

__device__ __forceinline__ unsigned short f2bf(float f) {
  union { float f; unsigned u; } x; x.f = f;
  unsigned r = x.u + 0x7FFFu + ((x.u >> 16) & 1u);
  return (unsigned short)(r >> 16);
}

// ---------------- prep kernels ----------------

// xb[b, t*196+n, d] = t_x + vmae_space_pos[n,d] + vmae_temporal_pos[t,d]  (bf16)
__global__ void prep_x(const float* __restrict__ t_x, const float* __restrict__ sp,
                       const float* __restrict__ tp, unsigned short* __restrict__ xb,
                       int total4) {
  int i = blockIdx.x * 256 + threadIdx.x;
  if (i >= total4) return;
  int d4 = (i % 192) * 4;
  int row = i / 192;            // b*1568 + l
  int l = row % LQ;
  int t = l / 196, n = l % 196;
  float4 a  = *(const float4*)(t_x + (size_t)i * 4);
  float4 s  = *(const float4*)(sp + n * 768 + d4);
  float4 tt = *(const float4*)(tp + t * 768 + d4);
  ushort4 o;
  o.x = f2bf(a.x + s.x + tt.x);
  o.y = f2bf(a.y + s.y + tt.y);
  o.z = f2bf(a.z + s.z + tt.z);
  o.w = f2bf(a.w + s.w + tt.w);
  *(ushort4*)(xb + (size_t)i * 4) = o;
}

// ab[b, na*8+ta, d] = audio[2+na, b*8+ta, d] + audio_space_pos[na,d] + audio_temporal_pos[ta,d]
__global__ void prep_a(const float* __restrict__ audio, const float* __restrict__ asp,
                       const float* __restrict__ atp, unsigned short* __restrict__ ab,
                       int total4) {
  int i = blockIdx.x * 256 + threadIdx.x;
  if (i >= total4) return;
  int d4 = (i % 192) * 4;
  int row = i / 192;            // b*1568 + (na*8+ta)
  int b = row / LK;
  int r2 = row % LK;
  int na = r2 >> 3, ta = r2 & 7;
  const float* src = audio + ((size_t)(2 + na) * 32 + b * 8 + ta) * 768 + d4;
  float4 a  = *(const float4*)src;
  float4 s  = *(const float4*)(asp + na * 768 + d4);
  float4 tt = *(const float4*)(atp + ta * 768 + d4);
  ushort4 o;
  o.x = f2bf(a.x + s.x + tt.x);
  o.y = f2bf(a.y + s.y + tt.y);
  o.z = f2bf(a.z + s.z + tt.z);
  o.w = f2bf(a.w + s.w + tt.w);
  *(ushort4*)(ab + (size_t)i * 4) = o;
}

__global__ void conv_bf16(const float* __restrict__ src, unsigned short* __restrict__ dst,
                          int n4) {
  int i = blockIdx.x * 256 + threadIdx.x;
  if (i >= n4) return;
  float4 v = *(const float4*)(src + (size_t)i * 4);
  ushort4 o;
  o.x = f2bf(v.x); o.y = f2bf(v.y); o.z = f2bf(v.z); o.w = f2bf(v.w);
  *(ushort4*)(dst + (size_t)i * 4) = o;
}

// ---------------- GEMM: C[i,o] = sum_k A[i,k]*W[o,k] + bias[o] ----------------
// mode 0: Q    -> out_a[((b*12+h)*1568+l)*64+hd] = bf16((C)*0.125), h=o>>6
// mode 1: KV   -> o<768:  K  at out_a[((b*12+h)*1568+l)*64+hd]
//                 o>=768: V^T at out_b[((b*12+h)*64+hd)*1568+l]
// mode 2: proj -> out_f[i*N+o] = C  (fp32)
__global__ __launch_bounds__(256, 2) void gemm_bt(
    const unsigned short* __restrict__ A, const unsigned short* __restrict__ W,
    const float* __restrict__ bias,
    unsigned short* __restrict__ out_a, unsigned short* __restrict__ out_b,
    float* __restrict__ out_f, int K, int N, int mode) {
  __shared__ __align__(16) unsigned short As[128 * 72];
  __shared__ __align__(16) unsigned short Bs[128 * 72];
  const int tid = threadIdx.x;
  const int lane = tid & 63, wave = tid >> 6;
  const int wm = wave & 1, wn = wave >> 1;
  const int l15 = lane & 15, quad = lane >> 4;
  const int row0 = blockIdx.x * 128;
  const int col0 = blockIdx.y * 128;

  f4v acc[4][4] = {};

  for (int k0 = 0; k0 < K; k0 += 64) {
    __syncthreads();
    for (int c = tid; c < 1024; c += 256) {
      int r = c >> 3, kc = c & 7;
      *(uint4*)(As + r * 72 + kc * 8) =
          *(const uint4*)(A + (size_t)(row0 + r) * K + k0 + kc * 8);
      *(uint4*)(Bs + r * 72 + kc * 8) =
          *(const uint4*)(W + (size_t)(col0 + r) * K + k0 + kc * 8);
    }
    __syncthreads();
#pragma unroll
    for (int kk = 0; kk < 2; ++kk) {
      s8v af[4], bf[4];
#pragma unroll
      for (int i = 0; i < 4; ++i) {
        af[i] = *(const s8v*)(As + (wm * 64 + i * 16 + l15) * 72 + kk * 32 + quad * 8);
        bf[i] = *(const s8v*)(Bs + (wn * 64 + i * 16 + l15) * 72 + kk * 32 + quad * 8);
      }
#pragma unroll
      for (int mi = 0; mi < 4; ++mi)
#pragma unroll
        for (int ni = 0; ni < 4; ++ni)
          acc[mi][ni] = __builtin_amdgcn_mfma_f32_16x16x32_bf16(af[mi], bf[ni],
                                                               acc[mi][ni], 0, 0, 0);
    }
  }

#pragma unroll
  for (int mi = 0; mi < 4; ++mi) {
    int rowg = row0 + wm * 64 + mi * 16 + quad * 4;
#pragma unroll
    for (int ni = 0; ni < 4; ++ni) {
      int colg = col0 + wn * 64 + ni * 16 + l15;
      float bv = bias[colg];
#pragma unroll
      for (int r = 0; r < 4; ++r) {
        float v = acc[mi][ni][r] + bv;
        int row = rowg + r;
        if (mode == 0) {
          v *= 0.125f;
          int b = row / LQ, l = row - b * LQ;
          int h = colg >> 6, hd = colg & 63;
          out_a[(((size_t)b * NH + h) * LQ + l) * 64 + hd] = f2bf(v);
        } else if (mode == 1) {
          int b = row / LK, l = row - b * LK;
          if (colg < 768) {
            int h = colg >> 6, hd = colg & 63;
            out_a[(((size_t)b * NH + h) * LK + l) * 64 + hd] = f2bf(v);
          } else {
            int oo = colg - 768;
            int h = oo >> 6, hd = oo & 63;
            out_b[(((size_t)b * NH + h) * 64 + hd) * LK + l] = f2bf(v);
          }
        } else {
          out_f[(size_t)row * N + colg] = v;
        }
      }
    }
  }
}

// ---------------- flash attention ----------------
// grid: (13, 48). block 256 = 4 waves; each wave: 32 q-rows (2 m-tiles).
// K-tile = 112 keys (14 exact tiles over Lk=1568); PV k padded 112->128 with zeros.
__global__ __launch_bounds__(256, 2) void attn(
    const unsigned short* __restrict__ Q, const unsigned short* __restrict__ Kg,
    const unsigned short* __restrict__ Vt, unsigned short* __restrict__ O) {
  __shared__ __align__(16) unsigned short Kl[112 * 72];
  __shared__ __align__(16) unsigned short Vl[64 * 136];
  __shared__ __align__(16) unsigned short Pl[4 * 16 * 136];
  const int tid = threadIdx.x;
  const int lane = tid & 63, wave = tid >> 6;
  const int l15 = lane & 15, quad = lane >> 4;
  const int bh = blockIdx.y;
  const int q0 = blockIdx.x * 128;
  const size_t base = (size_t)bh * LK * 64;

  // Q fragments (A layout), rows clamped for the tail tile
  s8v qf[2][2];
#pragma unroll
  for (int mt = 0; mt < 2; ++mt)
#pragma unroll
    for (int kk = 0; kk < 2; ++kk) {
      int row = q0 + wave * 32 + mt * 16 + l15;
      if (row > LQ - 1) row = LQ - 1;
      qf[mt][kk] = *(const s8v*)(Q + base + (size_t)row * 64 + kk * 32 + quad * 8);
    }

  // zero V pad columns 112..127 (written once; staging never touches them)
  if (tid < 128) {
    int d = tid >> 1, p = tid & 1;
    uint4 z; z.x = z.y = z.z = z.w = 0u;
    *(uint4*)(Vl + d * 136 + 112 + p * 8) = z;
  }

  float mrow[2][4], lrow[2][4];
#pragma unroll
  for (int mt = 0; mt < 2; ++mt)
#pragma unroll
    for (int r = 0; r < 4; ++r) { mrow[mt][r] = -3.0e38f; lrow[mt][r] = 0.0f; }
  f4v of[2][4] = {};

  for (int k0 = 0; k0 < LK; k0 += 112) {
    __syncthreads();
    for (int c = tid; c < 896; c += 256) {   // K tile: 112 rows x 64
      int r = c >> 3, kc = c & 7;
      *(uint4*)(Kl + r * 72 + kc * 8) =
          *(const uint4*)(Kg + base + (size_t)(k0 + r) * 64 + kc * 8);
    }
    for (int c = tid; c < 896; c += 256) {   // V^T tile: 64 rows x 112
      int d = c / 14, kc = c - d * 14;
      *(uint4*)(Vl + d * 136 + kc * 8) =
          *(const uint4*)(Vt + base + (size_t)d * LK + k0 + kc * 8);
    }
    __syncthreads();

    // S = Q K^T for this tile: per wave 32x112 in C-frags
    f4v sf[2][7] = {};
#pragma unroll
    for (int nt = 0; nt < 7; ++nt) {
#pragma unroll
      for (int kk = 0; kk < 2; ++kk) {
        s8v kf = *(const s8v*)(Kl + (nt * 16 + l15) * 72 + kk * 32 + quad * 8);
        sf[0][nt] = __builtin_amdgcn_mfma_f32_16x16x32_bf16(qf[0][kk], kf, sf[0][nt], 0, 0, 0);
        sf[1][nt] = __builtin_amdgcn_mfma_f32_16x16x32_bf16(qf[1][kk], kf, sf[1][nt], 0, 0, 0);
      }
    }

#pragma unroll
    for (int mt = 0; mt < 2; ++mt) {
      // row max over the 112 keys
      float mx[4];
#pragma unroll
      for (int r = 0; r < 4; ++r) {
        float v = sf[mt][0][r];
#pragma unroll
        for (int nt = 1; nt < 7; ++nt) v = fmaxf(v, sf[mt][nt][r]);
        mx[r] = v;
      }
#pragma unroll
      for (int off = 1; off < 16; off <<= 1)
#pragma unroll
        for (int r = 0; r < 4; ++r) mx[r] = fmaxf(mx[r], __shfl_xor(mx[r], off));

      float alpha[4], rs[4];
#pragma unroll
      for (int r = 0; r < 4; ++r) {
        float mnew = fmaxf(mrow[mt][r], mx[r]);
        alpha[r] = __expf(mrow[mt][r] - mnew);
        mrow[mt][r] = mnew;
        rs[r] = 0.0f;
      }
      // P = exp(S - m)
#pragma unroll
      for (int nt = 0; nt < 7; ++nt)
#pragma unroll
        for (int r = 0; r < 4; ++r) {
          float p = __expf(sf[mt][nt][r] - mrow[mt][r]);
          sf[mt][nt][r] = p;
          rs[r] += p;
        }
#pragma unroll
      for (int off = 1; off < 16; off <<= 1)
#pragma unroll
        for (int r = 0; r < 4; ++r) rs[r] += __shfl_xor(rs[r], off);
#pragma unroll
      for (int r = 0; r < 4; ++r) lrow[mt][r] = lrow[mt][r] * alpha[r] + rs[r];
      // rescale O
#pragma unroll
      for (int nd = 0; nd < 4; ++nd)
#pragma unroll
        for (int r = 0; r < 4; ++r) of[mt][nd][r] *= alpha[r];

      // P: C-layout -> LDS (per-wave private region) -> A-layout
      unsigned short* pw = Pl + wave * 16 * 136;
#pragma unroll
      for (int nt = 0; nt < 7; ++nt)
#pragma unroll
        for (int r = 0; r < 4; ++r)
          pw[(quad * 4 + r) * 136 + nt * 16 + l15] = f2bf(sf[mt][nt][r]);
#pragma unroll
      for (int r = 0; r < 4; ++r)
        pw[(quad * 4 + r) * 136 + 112 + l15] = 0;  // zero pad keys 112..127

      // O += P V
#pragma unroll
      for (int kc = 0; kc < 4; ++kc) {
        s8v pf = *(const s8v*)(pw + l15 * 136 + kc * 32 + quad * 8);
#pragma unroll
        for (int nd = 0; nd < 4; ++nd) {
          s8v vf = *(const s8v*)(Vl + (nd * 16 + l15) * 136 + kc * 32 + quad * 8);
          of[mt][nd] = __builtin_amdgcn_mfma_f32_16x16x32_bf16(pf, vf, of[mt][nd], 0, 0, 0);
        }
      }
    }
  }

  // epilogue: O /= l, write [b, row, h*64+hd] bf16
  const int b = bh / NH, h = bh - b * NH;
#pragma unroll
  for (int mt = 0; mt < 2; ++mt)
#pragma unroll
    for (int r = 0; r < 4; ++r) {
      int row = q0 + wave * 32 + mt * 16 + quad * 4 + r;
      if (row >= LQ) continue;
      float inv = 1.0f / lrow[mt][r];
#pragma unroll
      for (int nd = 0; nd < 4; ++nd) {
        float v = of[mt][nd][r] * inv;
        O[((size_t)(b * LQ) + row) * 768 + h * 64 + nd * 16 + l15] = f2bf(v);
      }
    }
}

// ---------------- launcher ----------------
extern "C" void kernel_launch(void* const* d_in, const int* in_sizes, int n_in,
                              void* d_out, int out_size, void* d_ws, size_t ws_size,
                              hipStream_t stream) {
  const float* t_x    = (const float*)d_in[0];
  const float* audio  = (const float*)d_in[1];
  const float* sp     = (const float*)d_in[2];
  const float* asp    = (const float*)d_in[3];
  const float* tp     = (const float*)d_in[4];
  const float* atp    = (const float*)d_in[5];
  const float* q_w    = (const float*)d_in[6];
  const float* q_b    = (const float*)d_in[7];
  const float* kv_w   = (const float*)d_in[8];
  const float* kv_b   = (const float*)d_in[9];
  const float* proj_w = (const float*)d_in[10];
  const float* proj_b = (const float*)d_in[11];
  float* out = (float*)d_out;

  char* ws = (char*)d_ws;
  size_t off = 0;
  auto alloc = [&](size_t bytes) -> void* {
    void* p = ws + off;
    off += (bytes + 255) & ~(size_t)255;
    return p;
  };
  const size_t TOK = 6272;  // B*1568
  unsigned short* xb  = (unsigned short*)alloc(TOK * 768 * 2);  // reused as O after Q-GEMM
  unsigned short* ab  = (unsigned short*)alloc(TOK * 768 * 2);
  unsigned short* wq  = (unsigned short*)alloc(768 * 768 * 2);
  unsigned short* wkv = (unsigned short*)alloc(1536 * 768 * 2);
  unsigned short* wp  = (unsigned short*)alloc(768 * 768 * 2);
  unsigned short* Qs  = (unsigned short*)alloc(TOK * 768 * 2);  // [B,H,Lq,64] scaled
  unsigned short* Kb  = (unsigned short*)alloc(TOK * 768 * 2);  // [B,H,Lk,64]
  unsigned short* Vb  = (unsigned short*)alloc(TOK * 768 * 2);  // [B,H,64,Lk]

  dim3 blk(256);
  conv_bf16<<<dim3((768 * 768 / 4 + 255) / 256), blk, 0, stream>>>(q_w, wq, 768 * 768 / 4);
  conv_bf16<<<dim3((1536 * 768 / 4 + 255) / 256), blk, 0, stream>>>(kv_w, wkv, 1536 * 768 / 4);
  conv_bf16<<<dim3((768 * 768 / 4 + 255) / 256), blk, 0, stream>>>(proj_w, wp, 768 * 768 / 4);

  int total4 = (int)(TOK * 192);
  prep_x<<<dim3((total4 + 255) / 256), blk, 0, stream>>>(t_x, sp, tp, xb, total4);
  prep_a<<<dim3((total4 + 255) / 256), blk, 0, stream>>>(audio, asp, atp, ab, total4);

  gemm_bt<<<dim3(49, 6), blk, 0, stream>>>(xb, wq, q_b, Qs, nullptr, nullptr, 768, 768, 0);
  gemm_bt<<<dim3(49, 12), blk, 0, stream>>>(ab, wkv, kv_b, Kb, Vb, nullptr, 768, 1536, 1);

  attn<<<dim3(13, 48), blk, 0, stream>>>(Qs, Kb, Vb, xb /* O overwrites xb */);

  gemm_bt<<<dim3(49, 6), blk, 0, stream>>>(xb, wp, proj_b, nullptr, nullptr, out, 768, 768, 2);
}

// Round 2
// 285.904 us; speedup vs baseline: 1.2356x; 1.2356x over previous
//
#include <hip/hip_runtime.h>

typedef short s8v __attribute__((ext_vector_type(8)));
typedef short s4v __attribute__((ext_vector_type(4)));
typedef float f4v __attribute__((ext_vector_type(4)));

#define LQ 1568
#define LK 1568
#define NH 12

__device__ __forceinline__ unsigned short f2bf(float f) {
  union { float f; unsigned u; } x; x.f = f;
  unsigned r = x.u + 0x7FFFu + ((x.u >> 16) & 1u);
  return (unsigned short)(r >> 16);
}

// ---------------- prep kernels ----------------

__global__ void prep_x(const float* __restrict__ t_x, const float* __restrict__ sp,
                       const float* __restrict__ tp, unsigned short* __restrict__ xb,
                       int total4) {
  int i = blockIdx.x * 256 + threadIdx.x;
  if (i >= total4) return;
  int d4 = (i % 192) * 4;
  int row = i / 192;            // b*1568 + l
  int l = row % LQ;
  int t = l / 196, n = l % 196;
  float4 a  = *(const float4*)(t_x + (size_t)i * 4);
  float4 s  = *(const float4*)(sp + n * 768 + d4);
  float4 tt = *(const float4*)(tp + t * 768 + d4);
  ushort4 o;
  o.x = f2bf(a.x + s.x + tt.x);
  o.y = f2bf(a.y + s.y + tt.y);
  o.z = f2bf(a.z + s.z + tt.z);
  o.w = f2bf(a.w + s.w + tt.w);
  *(ushort4*)(xb + (size_t)i * 4) = o;
}

__global__ void prep_a(const float* __restrict__ audio, const float* __restrict__ asp,
                       const float* __restrict__ atp, unsigned short* __restrict__ ab,
                       int total4) {
  int i = blockIdx.x * 256 + threadIdx.x;
  if (i >= total4) return;
  int d4 = (i % 192) * 4;
  int row = i / 192;            // b*1568 + (na*8+ta)
  int b = row / LK;
  int r2 = row % LK;
  int na = r2 >> 3, ta = r2 & 7;
  const float* src = audio + ((size_t)(2 + na) * 32 + b * 8 + ta) * 768 + d4;
  float4 a  = *(const float4*)src;
  float4 s  = *(const float4*)(asp + na * 768 + d4);
  float4 tt = *(const float4*)(atp + ta * 768 + d4);
  ushort4 o;
  o.x = f2bf(a.x + s.x + tt.x);
  o.y = f2bf(a.y + s.y + tt.y);
  o.z = f2bf(a.z + s.z + tt.z);
  o.w = f2bf(a.w + s.w + tt.w);
  *(ushort4*)(ab + (size_t)i * 4) = o;
}

__global__ void conv_bf16(const float* __restrict__ src, unsigned short* __restrict__ dst,
                          int n4) {
  int i = blockIdx.x * 256 + threadIdx.x;
  if (i >= n4) return;
  float4 v = *(const float4*)(src + (size_t)i * 4);
  ushort4 o;
  o.x = f2bf(v.x); o.y = f2bf(v.y); o.z = f2bf(v.z); o.w = f2bf(v.w);
  *(ushort4*)(dst + (size_t)i * 4) = o;
}

// ---------------- GEMM: C[i,o] = sum_k A[i,k]*W[o,k] + bias[o] ----------------
// mode 0: Q    -> out_a[((b*12+h)*1568+l)*64+hd] = bf16(C*0.125*log2e)
// mode 1: KV   -> o<768:  K  at out_a[((b*12+h)*1568+l)*64+hd]
//                 o>=768: V swizzled: out_b[(((b*12+h)*392 + (l>>2))*64 + hd)*4 + (l&3)]
// mode 2: proj -> out_f[i*N+o] = C  (fp32)
__global__ __launch_bounds__(256, 2) void gemm_bt(
    const unsigned short* __restrict__ A, const unsigned short* __restrict__ W,
    const float* __restrict__ bias,
    unsigned short* __restrict__ out_a, unsigned short* __restrict__ out_b,
    float* __restrict__ out_f, int K, int N, int mode) {
  __shared__ __align__(16) unsigned short As[128 * 72];
  __shared__ __align__(16) unsigned short Bs[128 * 72];
  const int tid = threadIdx.x;
  const int lane = tid & 63, wave = tid >> 6;
  const int wm = wave & 1, wn = wave >> 1;
  const int l15 = lane & 15, quad = lane >> 4;
  const int row0 = blockIdx.x * 128;
  const int col0 = blockIdx.y * 128;

  f4v acc[4][4] = {};

  for (int k0 = 0; k0 < K; k0 += 64) {
    __syncthreads();
    for (int c = tid; c < 1024; c += 256) {
      int r = c >> 3, kc = c & 7;
      *(uint4*)(As + r * 72 + kc * 8) =
          *(const uint4*)(A + (size_t)(row0 + r) * K + k0 + kc * 8);
      *(uint4*)(Bs + r * 72 + kc * 8) =
          *(const uint4*)(W + (size_t)(col0 + r) * K + k0 + kc * 8);
    }
    __syncthreads();
#pragma unroll
    for (int kk = 0; kk < 2; ++kk) {
      s8v af[4], bf[4];
#pragma unroll
      for (int i = 0; i < 4; ++i) {
        af[i] = *(const s8v*)(As + (wm * 64 + i * 16 + l15) * 72 + kk * 32 + quad * 8);
        bf[i] = *(const s8v*)(Bs + (wn * 64 + i * 16 + l15) * 72 + kk * 32 + quad * 8);
      }
#pragma unroll
      for (int mi = 0; mi < 4; ++mi)
#pragma unroll
        for (int ni = 0; ni < 4; ++ni)
          acc[mi][ni] = __builtin_amdgcn_mfma_f32_16x16x32_bf16(af[mi], bf[ni],
                                                               acc[mi][ni], 0, 0, 0);
    }
  }

#pragma unroll
  for (int mi = 0; mi < 4; ++mi) {
    int rowg = row0 + wm * 64 + mi * 16 + quad * 4;
#pragma unroll
    for (int ni = 0; ni < 4; ++ni) {
      int colg = col0 + wn * 64 + ni * 16 + l15;
      float bv = bias[colg];
      if (mode == 1 && colg >= 768) {
        // V path: pack 4 consecutive rows (k%4) into one 8B store, swizzled layout
        int oo = colg - 768;
        int h = oo >> 6, hd = oo & 63;
        int b = rowg / LK, l0 = rowg - b * LK;   // rowg % 4 == 0, no b-crossing
        ushort4 pk;
        pk.x = f2bf(acc[mi][ni][0] + bv);
        pk.y = f2bf(acc[mi][ni][1] + bv);
        pk.z = f2bf(acc[mi][ni][2] + bv);
        pk.w = f2bf(acc[mi][ni][3] + bv);
        *(ushort4*)(out_b + ((((size_t)b * NH + h) * 392 + (l0 >> 2)) * 64 + hd) * 4) = pk;
        continue;
      }
#pragma unroll
      for (int r = 0; r < 4; ++r) {
        float v = acc[mi][ni][r] + bv;
        int row = rowg + r;
        if (mode == 0) {
          v *= 0.18033688011112042f;   // 0.125 * log2(e) folded for exp2 softmax
          int b = row / LQ, l = row - b * LQ;
          int h = colg >> 6, hd = colg & 63;
          out_a[(((size_t)b * NH + h) * LQ + l) * 64 + hd] = f2bf(v);
        } else if (mode == 1) {
          int b = row / LK, l = row - b * LK;
          int h = colg >> 6, hd = colg & 63;
          out_a[(((size_t)b * NH + h) * LK + l) * 64 + hd] = f2bf(v);
        } else {
          out_f[(size_t)row * N + colg] = v;
        }
      }
    }
  }
}

// ---------------- flash attention (S^T trick, no P round-trip, no max pass) ----
// grid: (13, 48). block 256 = 4 waves; each wave: 32 q-rows (2 mt of 16).
// K-tile = 112 keys (14 exact tiles). S^T = K·Q^T so P lands in the exact
// A-operand layout of mfma_f32_16x16x16_bf16 (k = quad*4+reg). V pre-swizzled
// [k/4][d][k%4] so PV B-frags are contiguous 8B LDS reads.
__global__ __launch_bounds__(256, 3) void attn(
    const unsigned short* __restrict__ Q, const unsigned short* __restrict__ Kg,
    const unsigned short* __restrict__ Vsw, unsigned short* __restrict__ O) {
  __shared__ __align__(16) unsigned short Kl[112 * 72];
  __shared__ __align__(16) unsigned short Vl[112 * 64];
  const int tid = threadIdx.x;
  const int lane = tid & 63, wave = tid >> 6;
  const int l15 = lane & 15, quad = lane >> 4;
  const int bh = blockIdx.y;
  const int q0 = blockIdx.x * 128;
  const size_t base = (size_t)bh * LK * 64;

  // Q fragments (B-operand of S^T = K Q^T; layout identical to A-frag addressing)
  s8v qf[2][2];
#pragma unroll
  for (int mt = 0; mt < 2; ++mt)
#pragma unroll
    for (int kk = 0; kk < 2; ++kk) {
      int row = q0 + wave * 32 + mt * 16 + l15;
      if (row > LQ - 1) row = LQ - 1;
      qf[mt][kk] = *(const s8v*)(Q + base + (size_t)row * 64 + kk * 32 + quad * 8);
    }

  f4v of[2][4] = {};
  float lr[2] = {0.0f, 0.0f};   // per-lane partial softmax denominators

  for (int k0 = 0; k0 < LK; k0 += 112) {
    __syncthreads();
    for (int c = tid; c < 896; c += 256) {   // K tile: 112 rows x 64, stride 72
      int r = c >> 3, kc = c & 7;
      *(uint4*)(Kl + r * 72 + kc * 8) =
          *(const uint4*)(Kg + base + (size_t)(k0 + r) * 64 + kc * 8);
    }
    {
      const uint4* src = (const uint4*)(Vsw + base + (size_t)k0 * 64);
      uint4* dst = (uint4*)Vl;
      for (int c = tid; c < 896; c += 256) dst[c] = src[c];  // contiguous copy
    }
    __syncthreads();

#pragma unroll
    for (int nt = 0; nt < 7; ++nt) {
      s8v kf0 = *(const s8v*)(Kl + (nt * 16 + l15) * 72 + quad * 8);
      s8v kf1 = *(const s8v*)(Kl + (nt * 16 + l15) * 72 + 32 + quad * 8);
      s4v pf[2];
#pragma unroll
      for (int mt = 0; mt < 2; ++mt) {
        f4v s = {};
        s = __builtin_amdgcn_mfma_f32_16x16x32_bf16(kf0, qf[mt][0], s, 0, 0, 0);
        s = __builtin_amdgcn_mfma_f32_16x16x32_bf16(kf1, qf[mt][1], s, 0, 0, 0);
        // P = exp2(S)  (log2e folded into Q scale; no max subtraction needed)
        float p0 = __builtin_amdgcn_exp2f(s[0]);
        float p1 = __builtin_amdgcn_exp2f(s[1]);
        float p2 = __builtin_amdgcn_exp2f(s[2]);
        float p3 = __builtin_amdgcn_exp2f(s[3]);
        lr[mt] += (p0 + p1) + (p2 + p3);
        union { float f; unsigned u; } a0, a1, a2, a3;
        a0.f = p0; a1.f = p1; a2.f = p2; a3.f = p3;
        union { uint2 u; s4v s; } pk;
        pk.u.x = __builtin_amdgcn_perm(a1.u, a0.u, 0x07060302u);  // [p1.hi|p0.hi]
        pk.u.y = __builtin_amdgcn_perm(a3.u, a2.u, 0x07060302u);  // [p3.hi|p2.hi]
        pf[mt] = pk.s;
      }
#pragma unroll
      for (int nd = 0; nd < 4; ++nd) {
        s4v vf = *(const s4v*)(Vl + ((nt * 4 + quad) << 8) + ((nd * 16 + l15) << 2));
        of[0][nd] = __builtin_amdgcn_mfma_f32_16x16x16bf16_1k(pf[0], vf, of[0][nd], 0, 0, 0);
        of[1][nd] = __builtin_amdgcn_mfma_f32_16x16x16bf16_1k(pf[1], vf, of[1][nd], 0, 0, 0);
      }
    }
  }

  // reduce softmax denominators across quads (keys were split by quad)
#pragma unroll
  for (int mt = 0; mt < 2; ++mt) {
    lr[mt] += __shfl_xor(lr[mt], 16);
    lr[mt] += __shfl_xor(lr[mt], 32);
  }

  // epilogue: O /= l, write [b, row, h*64+hd] bf16
  const int b = bh / NH, h = bh - b * NH;
#pragma unroll
  for (int mt = 0; mt < 2; ++mt)
#pragma unroll
    for (int r = 0; r < 4; ++r) {
      int row = q0 + wave * 32 + mt * 16 + quad * 4 + r;
      if (row >= LQ) continue;
      float inv = 1.0f / __shfl(lr[mt], quad * 4 + r);
#pragma unroll
      for (int nd = 0; nd < 4; ++nd) {
        float v = of[mt][nd][r] * inv;
        O[((size_t)(b * LQ) + row) * 768 + h * 64 + nd * 16 + l15] = f2bf(v);
      }
    }
}

// ---------------- launcher ----------------
extern "C" void kernel_launch(void* const* d_in, const int* in_sizes, int n_in,
                              void* d_out, int out_size, void* d_ws, size_t ws_size,
                              hipStream_t stream) {
  const float* t_x    = (const float*)d_in[0];
  const float* audio  = (const float*)d_in[1];
  const float* sp     = (const float*)d_in[2];
  const float* asp    = (const float*)d_in[3];
  const float* tp     = (const float*)d_in[4];
  const float* atp    = (const float*)d_in[5];
  const float* q_w    = (const float*)d_in[6];
  const float* q_b    = (const float*)d_in[7];
  const float* kv_w   = (const float*)d_in[8];
  const float* kv_b   = (const float*)d_in[9];
  const float* proj_w = (const float*)d_in[10];
  const float* proj_b = (const float*)d_in[11];
  float* out = (float*)d_out;

  char* ws = (char*)d_ws;
  size_t off = 0;
  auto alloc = [&](size_t bytes) -> void* {
    void* p = ws + off;
    off += (bytes + 255) & ~(size_t)255;
    return p;
  };
  const size_t TOK = 6272;  // B*1568
  unsigned short* xb  = (unsigned short*)alloc(TOK * 768 * 2);  // reused as O after Q-GEMM
  unsigned short* ab  = (unsigned short*)alloc(TOK * 768 * 2);
  unsigned short* wq  = (unsigned short*)alloc(768 * 768 * 2);
  unsigned short* wkv = (unsigned short*)alloc(1536 * 768 * 2);
  unsigned short* wp  = (unsigned short*)alloc(768 * 768 * 2);
  unsigned short* Qs  = (unsigned short*)alloc(TOK * 768 * 2);  // [B,H,Lq,64] scaled
  unsigned short* Kb  = (unsigned short*)alloc(TOK * 768 * 2);  // [B,H,Lk,64]
  unsigned short* Vb  = (unsigned short*)alloc(TOK * 768 * 2);  // [B,H,Lk/4,64,4] swizzled

  dim3 blk(256);
  conv_bf16<<<dim3((768 * 768 / 4 + 255) / 256), blk, 0, stream>>>(q_w, wq, 768 * 768 / 4);
  conv_bf16<<<dim3((1536 * 768 / 4 + 255) / 256), blk, 0, stream>>>(kv_w, wkv, 1536 * 768 / 4);
  conv_bf16<<<dim3((768 * 768 / 4 + 255) / 256), blk, 0, stream>>>(proj_w, wp, 768 * 768 / 4);

  int total4 = (int)(TOK * 192);
  prep_x<<<dim3((total4 + 255) / 256), blk, 0, stream>>>(t_x, sp, tp, xb, total4);
  prep_a<<<dim3((total4 + 255) / 256), blk, 0, stream>>>(audio, asp, atp, ab, total4);

  gemm_bt<<<dim3(49, 6), blk, 0, stream>>>(xb, wq, q_b, Qs, nullptr, nullptr, 768, 768, 0);
  gemm_bt<<<dim3(49, 12), blk, 0, stream>>>(ab, wkv, kv_b, Kb, Vb, nullptr, 768, 1536, 1);

  attn<<<dim3(13, 48), blk, 0, stream>>>(Qs, Kb, Vb, xb /* O overwrites xb */);

  gemm_bt<<<dim3(49, 6), blk, 0, stream>>>(xb, wp, proj_b, nullptr, nullptr, out, 768, 768, 2);
}

// Round 4
// 245.360 us; speedup vs baseline: 1.4398x; 1.1652x over previous
//
#include <hip/hip_runtime.h>

typedef short s8v __attribute__((ext_vector_type(8)));
typedef short s4v __attribute__((ext_vector_type(4)));
typedef float f4v __attribute__((ext_vector_type(4)));

#define LQ 1568
#define LK 1568
#define NH 12

__device__ __forceinline__ unsigned short f2bf(float f) {
  union { float f; unsigned u; } x; x.f = f;
  unsigned r = x.u + 0x7FFFu + ((x.u >> 16) & 1u);
  return (unsigned short)(r >> 16);
}

// ---------------- prep: pos-embed add + bf16 cast (x and audio fused) --------
__global__ void prep_xa(const float* __restrict__ t_x, const float* __restrict__ audio,
                        const float* __restrict__ sp, const float* __restrict__ asp,
                        const float* __restrict__ tp, const float* __restrict__ atp,
                        unsigned short* __restrict__ xb, unsigned short* __restrict__ ab,
                        int total4) {
  int i = blockIdx.x * 256 + threadIdx.x;
  if (i >= 2 * total4) return;
  if (i < total4) {
    int d4 = (i % 192) * 4;
    int row = i / 192;            // b*1568 + l
    int l = row % LQ;
    int t = l / 196, n = l % 196;
    float4 a  = *(const float4*)(t_x + (size_t)i * 4);
    float4 s  = *(const float4*)(sp + n * 768 + d4);
    float4 tt = *(const float4*)(tp + t * 768 + d4);
    ushort4 o;
    o.x = f2bf(a.x + s.x + tt.x);
    o.y = f2bf(a.y + s.y + tt.y);
    o.z = f2bf(a.z + s.z + tt.z);
    o.w = f2bf(a.w + s.w + tt.w);
    *(ushort4*)(xb + (size_t)i * 4) = o;
  } else {
    i -= total4;
    int d4 = (i % 192) * 4;
    int row = i / 192;            // b*1568 + (na*8+ta)
    int b = row / LK;
    int r2 = row % LK;
    int na = r2 >> 3, ta = r2 & 7;
    const float* src = audio + ((size_t)(2 + na) * 32 + b * 8 + ta) * 768 + d4;
    float4 a  = *(const float4*)src;
    float4 s  = *(const float4*)(asp + na * 768 + d4);
    float4 tt = *(const float4*)(atp + ta * 768 + d4);
    ushort4 o;
    o.x = f2bf(a.x + s.x + tt.x);
    o.y = f2bf(a.y + s.y + tt.y);
    o.z = f2bf(a.z + s.z + tt.z);
    o.w = f2bf(a.w + s.w + tt.w);
    *(ushort4*)(ab + (size_t)i * 4) = o;
  }
}

// all three weight matrices -> bf16 in one launch
__global__ void conv_w(const float* __restrict__ q_w, const float* __restrict__ kv_w,
                       const float* __restrict__ proj_w, unsigned short* __restrict__ wq,
                       unsigned short* __restrict__ wkv, unsigned short* __restrict__ wp) {
  const int n1 = 768 * 768 / 4, n2 = 1536 * 768 / 4;
  int i = blockIdx.x * 256 + threadIdx.x;
  const float* src; unsigned short* dst; int j = i;
  if (i < n1)               { src = q_w;    dst = wq;  }
  else if (i < n1 + n2)     { src = kv_w;   dst = wkv; j = i - n1; }
  else if (i < 2 * n1 + n2) { src = proj_w; dst = wp;  j = i - n1 - n2; }
  else return;
  float4 v = *(const float4*)(src + (size_t)j * 4);
  ushort4 o;
  o.x = f2bf(v.x); o.y = f2bf(v.y); o.z = f2bf(v.z); o.w = f2bf(v.w);
  *(ushort4*)(dst + (size_t)j * 4) = o;
}

// ---------------- shared GEMM mainloop: m97 structure ------------------------
// 128x128 tile, BK=64, unpadded stride-64 LDS, global_load_lds dwordx4 staging.
// Staging coords MUST be linear in tid: LDS elem offset = tid*8 (lane x 16B),
// i.e. lr = tid>>3, lc = (tid&7)*8 -- the wave-uniform-base constraint (m104).
__device__ __forceinline__ void gemm_mainloop(
    const unsigned short* __restrict__ A, const unsigned short* __restrict__ W,
    int K, int row0, int col0,
    unsigned short* As, unsigned short* Bs, f4v acc[4][4]) {
  const int tid = threadIdx.x;
  const int lane = tid & 63, wave = tid >> 6;
  const int wm = wave & 1, wn = wave >> 1;
  const int l15 = lane & 15, quad = lane >> 4;
  const int lr = tid >> 3, lc = (tid & 7) * 8;   // flat offset = tid*8 elems

  for (int k0 = 0; k0 < K; k0 += 64) {
    __syncthreads();
#pragma unroll
    for (int it = 0; it < 4; ++it) {
      int row = lr + it * 32;                    // 32 rows per issue x 4
      __builtin_amdgcn_global_load_lds(
          (const __attribute__((address_space(1))) unsigned int*)(A + (size_t)(row0 + row) * K + k0 + lc),
          (__attribute__((address_space(3))) unsigned int*)(As + row * 64 + lc), 16, 0, 0);
      __builtin_amdgcn_global_load_lds(
          (const __attribute__((address_space(1))) unsigned int*)(W + (size_t)(col0 + row) * K + k0 + lc),
          (__attribute__((address_space(3))) unsigned int*)(Bs + row * 64 + lc), 16, 0, 0);
    }
    __syncthreads();
#pragma unroll
    for (int kk = 0; kk < 2; ++kk) {
      s8v af[4], bf[4];
#pragma unroll
      for (int i = 0; i < 4; ++i) {
        af[i] = *(const s8v*)(As + (wm * 64 + i * 16 + l15) * 64 + kk * 32 + quad * 8);
        bf[i] = *(const s8v*)(Bs + (wn * 64 + i * 16 + l15) * 64 + kk * 32 + quad * 8);
      }
#pragma unroll
      for (int mi = 0; mi < 4; ++mi)
#pragma unroll
        for (int ni = 0; ni < 4; ++ni)
          acc[mi][ni] = __builtin_amdgcn_mfma_f32_16x16x32_bf16(af[mi], bf[ni],
                                                               acc[mi][ni], 0, 0, 0);
    }
  }
}

// ---------------- fused Q + KV projection GEMM -------------------------------
// grid (49, 18): y<6 -> Q cols, y>=6 -> KV cols.
__global__ __launch_bounds__(256, 2) void gemm_qkv(
    const unsigned short* __restrict__ xb, const unsigned short* __restrict__ ab,
    const unsigned short* __restrict__ wq, const unsigned short* __restrict__ wkv,
    const float* __restrict__ q_b, const float* __restrict__ kv_b,
    unsigned short* __restrict__ Qs, unsigned short* __restrict__ Kb,
    unsigned short* __restrict__ Vb) {
  __shared__ __align__(16) unsigned short As[128 * 64];
  __shared__ __align__(16) unsigned short Bs[128 * 64];
  const int tid = threadIdx.x;
  const int lane = tid & 63, wave = tid >> 6;
  const int wm = wave & 1, wn = wave >> 1;
  const int l15 = lane & 15, quad = lane >> 4;
  const int row0 = blockIdx.x * 128;
  const int y = blockIdx.y;
  const bool isQ = (y < 6);
  const int col0 = (isQ ? y : y - 6) * 128;
  const unsigned short* A = isQ ? xb : ab;
  const unsigned short* W = isQ ? wq : wkv;
  const float* bias = isQ ? q_b : kv_b;

  f4v acc[4][4] = {};
  gemm_mainloop(A, W, 768, row0, col0, As, Bs, acc);

#pragma unroll
  for (int mi = 0; mi < 4; ++mi) {
    int rowg = row0 + wm * 64 + mi * 16 + quad * 4;
#pragma unroll
    for (int ni = 0; ni < 4; ++ni) {
      int colg = col0 + wn * 64 + ni * 16 + l15;
      float bv = bias[colg];
      if (!isQ && colg >= 768) {
        // V: pack 4 consecutive k-rows into one 8B store, swizzled layout
        int oo = colg - 768;
        int h = oo >> 6, hd = oo & 63;
        int b = rowg / LK, l0 = rowg - b * LK;   // rowg%4==0, no b-crossing
        ushort4 pk;
        pk.x = f2bf(acc[mi][ni][0] + bv);
        pk.y = f2bf(acc[mi][ni][1] + bv);
        pk.z = f2bf(acc[mi][ni][2] + bv);
        pk.w = f2bf(acc[mi][ni][3] + bv);
        *(ushort4*)(Vb + ((((size_t)b * NH + h) * 392 + (l0 >> 2)) * 64 + hd) * 4) = pk;
        continue;
      }
#pragma unroll
      for (int r = 0; r < 4; ++r) {
        float v = acc[mi][ni][r] + bv;
        int row = rowg + r;
        int b = row / LQ, l = row - b * LQ;
        int h = colg >> 6, hd = colg & 63;
        if (isQ) {
          v *= 0.18033688011112042f;   // 0.125 * log2(e) for exp2 softmax
          Qs[(((size_t)b * NH + h) * LQ + l) * 64 + hd] = f2bf(v);
        } else {
          Kb[(((size_t)b * NH + h) * LK + l) * 64 + hd] = f2bf(v);
        }
      }
    }
  }
}

// ---------------- output projection GEMM (fp32 out) --------------------------
__global__ __launch_bounds__(256, 2) void gemm_proj(
    const unsigned short* __restrict__ A, const unsigned short* __restrict__ W,
    const float* __restrict__ bias, float* __restrict__ out) {
  __shared__ __align__(16) unsigned short As[128 * 64];
  __shared__ __align__(16) unsigned short Bs[128 * 64];
  const int tid = threadIdx.x;
  const int lane = tid & 63, wave = tid >> 6;
  const int wm = wave & 1, wn = wave >> 1;
  const int l15 = lane & 15, quad = lane >> 4;
  const int row0 = blockIdx.x * 128;
  const int col0 = blockIdx.y * 128;

  f4v acc[4][4] = {};
  gemm_mainloop(A, W, 768, row0, col0, As, Bs, acc);

#pragma unroll
  for (int mi = 0; mi < 4; ++mi) {
    int rowg = row0 + wm * 64 + mi * 16 + quad * 4;
#pragma unroll
    for (int ni = 0; ni < 4; ++ni) {
      int colg = col0 + wn * 64 + ni * 16 + l15;
      float bv = bias[colg];
#pragma unroll
      for (int r = 0; r < 4; ++r)
        out[(size_t)(rowg + r) * 768 + colg] = acc[mi][ni][r] + bv;
    }
  }
}

// ---------------- flash attention (S^T trick, unchanged from R2) -------------
__global__ __launch_bounds__(256, 3) void attn(
    const unsigned short* __restrict__ Q, const unsigned short* __restrict__ Kg,
    const unsigned short* __restrict__ Vsw, unsigned short* __restrict__ O) {
  __shared__ __align__(16) unsigned short Kl[112 * 72];
  __shared__ __align__(16) unsigned short Vl[112 * 64];
  const int tid = threadIdx.x;
  const int lane = tid & 63, wave = tid >> 6;
  const int l15 = lane & 15, quad = lane >> 4;
  const int bh = blockIdx.y;
  const int q0 = blockIdx.x * 128;
  const size_t base = (size_t)bh * LK * 64;

  s8v qf[2][2];
#pragma unroll
  for (int mt = 0; mt < 2; ++mt)
#pragma unroll
    for (int kk = 0; kk < 2; ++kk) {
      int row = q0 + wave * 32 + mt * 16 + l15;
      if (row > LQ - 1) row = LQ - 1;
      qf[mt][kk] = *(const s8v*)(Q + base + (size_t)row * 64 + kk * 32 + quad * 8);
    }

  f4v of[2][4] = {};
  float lr[2] = {0.0f, 0.0f};

  for (int k0 = 0; k0 < LK; k0 += 112) {
    __syncthreads();
    for (int c = tid; c < 896; c += 256) {   // K tile: 112 x 64, stride 72
      int r = c >> 3, kc = c & 7;
      *(uint4*)(Kl + r * 72 + kc * 8) =
          *(const uint4*)(Kg + base + (size_t)(k0 + r) * 64 + kc * 8);
    }
    {
      const uint4* src = (const uint4*)(Vsw + base + (size_t)k0 * 64);
      uint4* dst = (uint4*)Vl;
      for (int c = tid; c < 896; c += 256) dst[c] = src[c];
    }
    __syncthreads();

#pragma unroll
    for (int nt = 0; nt < 7; ++nt) {
      s8v kf0 = *(const s8v*)(Kl + (nt * 16 + l15) * 72 + quad * 8);
      s8v kf1 = *(const s8v*)(Kl + (nt * 16 + l15) * 72 + 32 + quad * 8);
      s4v pf[2];
#pragma unroll
      for (int mt = 0; mt < 2; ++mt) {
        f4v s = {};
        s = __builtin_amdgcn_mfma_f32_16x16x32_bf16(kf0, qf[mt][0], s, 0, 0, 0);
        s = __builtin_amdgcn_mfma_f32_16x16x32_bf16(kf1, qf[mt][1], s, 0, 0, 0);
        float p0 = __builtin_amdgcn_exp2f(s[0]);
        float p1 = __builtin_amdgcn_exp2f(s[1]);
        float p2 = __builtin_amdgcn_exp2f(s[2]);
        float p3 = __builtin_amdgcn_exp2f(s[3]);
        lr[mt] += (p0 + p1) + (p2 + p3);
        union { float f; unsigned u; } a0, a1, a2, a3;
        a0.f = p0; a1.f = p1; a2.f = p2; a3.f = p3;
        union { uint2 u; s4v s; } pk;
        pk.u.x = __builtin_amdgcn_perm(a1.u, a0.u, 0x07060302u);
        pk.u.y = __builtin_amdgcn_perm(a3.u, a2.u, 0x07060302u);
        pf[mt] = pk.s;
      }
#pragma unroll
      for (int nd = 0; nd < 4; ++nd) {
        s4v vf = *(const s4v*)(Vl + ((nt * 4 + quad) << 8) + ((nd * 16 + l15) << 2));
        of[0][nd] = __builtin_amdgcn_mfma_f32_16x16x16bf16_1k(pf[0], vf, of[0][nd], 0, 0, 0);
        of[1][nd] = __builtin_amdgcn_mfma_f32_16x16x16bf16_1k(pf[1], vf, of[1][nd], 0, 0, 0);
      }
    }
  }

#pragma unroll
  for (int mt = 0; mt < 2; ++mt) {
    lr[mt] += __shfl_xor(lr[mt], 16);
    lr[mt] += __shfl_xor(lr[mt], 32);
  }

  const int b = bh / NH, h = bh - b * NH;
#pragma unroll
  for (int mt = 0; mt < 2; ++mt)
#pragma unroll
    for (int r = 0; r < 4; ++r) {
      int row = q0 + wave * 32 + mt * 16 + quad * 4 + r;
      if (row >= LQ) continue;
      float inv = 1.0f / __shfl(lr[mt], quad * 4 + r);
#pragma unroll
      for (int nd = 0; nd < 4; ++nd) {
        float v = of[mt][nd][r] * inv;
        O[((size_t)(b * LQ) + row) * 768 + h * 64 + nd * 16 + l15] = f2bf(v);
      }
    }
}

// ---------------- launcher ----------------
extern "C" void kernel_launch(void* const* d_in, const int* in_sizes, int n_in,
                              void* d_out, int out_size, void* d_ws, size_t ws_size,
                              hipStream_t stream) {
  const float* t_x    = (const float*)d_in[0];
  const float* audio  = (const float*)d_in[1];
  const float* sp     = (const float*)d_in[2];
  const float* asp    = (const float*)d_in[3];
  const float* tp     = (const float*)d_in[4];
  const float* atp    = (const float*)d_in[5];
  const float* q_w    = (const float*)d_in[6];
  const float* q_b    = (const float*)d_in[7];
  const float* kv_w   = (const float*)d_in[8];
  const float* kv_b   = (const float*)d_in[9];
  const float* proj_w = (const float*)d_in[10];
  const float* proj_b = (const float*)d_in[11];
  float* out = (float*)d_out;

  char* ws = (char*)d_ws;
  size_t off = 0;
  auto alloc = [&](size_t bytes) -> void* {
    void* p = ws + off;
    off += (bytes + 255) & ~(size_t)255;
    return p;
  };
  const size_t TOK = 6272;  // B*1568
  unsigned short* xb  = (unsigned short*)alloc(TOK * 768 * 2);  // reused as O after attn
  unsigned short* ab  = (unsigned short*)alloc(TOK * 768 * 2);
  unsigned short* wq  = (unsigned short*)alloc(768 * 768 * 2);
  unsigned short* wkv = (unsigned short*)alloc(1536 * 768 * 2);
  unsigned short* wp  = (unsigned short*)alloc(768 * 768 * 2);
  unsigned short* Qs  = (unsigned short*)alloc(TOK * 768 * 2);  // [B,H,Lq,64] scaled
  unsigned short* Kb  = (unsigned short*)alloc(TOK * 768 * 2);  // [B,H,Lk,64]
  unsigned short* Vb  = (unsigned short*)alloc(TOK * 768 * 2);  // [B,H,Lk/4,64,4] swizzled

  dim3 blk(256);
  const int n1 = 768 * 768 / 4, n2 = 1536 * 768 / 4;
  conv_w<<<dim3((2 * n1 + n2 + 255) / 256), blk, 0, stream>>>(q_w, kv_w, proj_w, wq, wkv, wp);

  int total4 = (int)(TOK * 192);
  prep_xa<<<dim3((2 * total4 + 255) / 256), blk, 0, stream>>>(t_x, audio, sp, asp, tp, atp,
                                                              xb, ab, total4);

  gemm_qkv<<<dim3(49, 18), blk, 0, stream>>>(xb, ab, wq, wkv, q_b, kv_b, Qs, Kb, Vb);

  attn<<<dim3(13, 48), blk, 0, stream>>>(Qs, Kb, Vb, xb /* O overwrites xb */);

  gemm_proj<<<dim3(49, 6), blk, 0, stream>>>(xb, wp, proj_b, out);
}

// Round 5
// 240.857 us; speedup vs baseline: 1.4667x; 1.0187x over previous
//
#include <hip/hip_runtime.h>

typedef short s8v __attribute__((ext_vector_type(8)));
typedef short s4v __attribute__((ext_vector_type(4)));
typedef float f4v __attribute__((ext_vector_type(4)));

#define LQ 1568
#define LK 1568
#define NH 12
#define LQP 1664   // 13*128 padded q-rows per head

__device__ __forceinline__ unsigned short f2bf(float f) {
  union { float f; unsigned u; } x; x.f = f;
  unsigned r = x.u + 0x7FFFu + ((x.u >> 16) & 1u);
  return (unsigned short)(r >> 16);
}
__device__ __forceinline__ float bf2f(unsigned short s) {
  union { unsigned u; float f; } x; x.u = ((unsigned)s) << 16;
  return x.f;
}

// ---------------- prep: weights->bf16 + pos-embed adds, one launch ----------
__global__ void prep_all(const float* __restrict__ t_x, const float* __restrict__ audio,
                         const float* __restrict__ sp, const float* __restrict__ asp,
                         const float* __restrict__ tp, const float* __restrict__ atp,
                         const float* __restrict__ q_w, const float* __restrict__ kv_w,
                         const float* __restrict__ proj_w,
                         unsigned short* __restrict__ xb, unsigned short* __restrict__ ab,
                         unsigned short* __restrict__ wq, unsigned short* __restrict__ wkv,
                         unsigned short* __restrict__ wp, int total4) {
  const int n1 = 768 * 768 / 4, n2 = 1536 * 768 / 4;
  const int nconv = 2 * n1 + n2;
  int i = blockIdx.x * 256 + threadIdx.x;
  if (i < nconv) {
    const float* src; unsigned short* dst; int j = i;
    if (i < n1)           { src = q_w;    dst = wq;  }
    else if (i < n1 + n2) { src = kv_w;   dst = wkv; j = i - n1; }
    else                  { src = proj_w; dst = wp;  j = i - n1 - n2; }
    float4 v = *(const float4*)(src + (size_t)j * 4);
    ushort4 o;
    o.x = f2bf(v.x); o.y = f2bf(v.y); o.z = f2bf(v.z); o.w = f2bf(v.w);
    *(ushort4*)(dst + (size_t)j * 4) = o;
    return;
  }
  i -= nconv;
  if (i >= 2 * total4) return;
  if (i < total4) {
    int d4 = (i % 192) * 4;
    int row = i / 192;            // b*1568 + l
    int l = row % LQ;
    int t = l / 196, n = l % 196;
    float4 a  = *(const float4*)(t_x + (size_t)i * 4);
    float4 s  = *(const float4*)(sp + n * 768 + d4);
    float4 tt = *(const float4*)(tp + t * 768 + d4);
    ushort4 o;
    o.x = f2bf(a.x + s.x + tt.x);
    o.y = f2bf(a.y + s.y + tt.y);
    o.z = f2bf(a.z + s.z + tt.z);
    o.w = f2bf(a.w + s.w + tt.w);
    *(ushort4*)(xb + (size_t)i * 4) = o;
  } else {
    i -= total4;
    int d4 = (i % 192) * 4;
    int row = i / 192;            // b*1568 + (na*8+ta)
    int b = row / LK;
    int r2 = row % LK;
    int na = r2 >> 3, ta = r2 & 7;
    const float* src = audio + ((size_t)(2 + na) * 32 + b * 8 + ta) * 768 + d4;
    float4 a  = *(const float4*)src;
    float4 s  = *(const float4*)(asp + na * 768 + d4);
    float4 tt = *(const float4*)(atp + ta * 768 + d4);
    ushort4 o;
    o.x = f2bf(a.x + s.x + tt.x);
    o.y = f2bf(a.y + s.y + tt.y);
    o.z = f2bf(a.z + s.z + tt.z);
    o.w = f2bf(a.w + s.w + tt.w);
    *(ushort4*)(ab + (size_t)i * 4) = o;
  }
}

// ---------------- shared GEMM mainloop: m97 structure ------------------------
__device__ __forceinline__ void gemm_mainloop(
    const unsigned short* __restrict__ A, const unsigned short* __restrict__ W,
    int K, int row0, int col0,
    unsigned short* As, unsigned short* Bs, f4v acc[4][4]) {
  const int tid = threadIdx.x;
  const int lane = tid & 63, wave = tid >> 6;
  const int wm = wave & 1, wn = wave >> 1;
  const int l15 = lane & 15, quad = lane >> 4;
  const int lr = tid >> 3, lc = (tid & 7) * 8;   // flat LDS offset = tid*8 elems

  for (int k0 = 0; k0 < K; k0 += 64) {
    __syncthreads();
#pragma unroll
    for (int it = 0; it < 4; ++it) {
      int row = lr + it * 32;
      __builtin_amdgcn_global_load_lds(
          (const __attribute__((address_space(1))) unsigned int*)(A + (size_t)(row0 + row) * K + k0 + lc),
          (__attribute__((address_space(3))) unsigned int*)(As + row * 64 + lc), 16, 0, 0);
      __builtin_amdgcn_global_load_lds(
          (const __attribute__((address_space(1))) unsigned int*)(W + (size_t)(col0 + row) * K + k0 + lc),
          (__attribute__((address_space(3))) unsigned int*)(Bs + row * 64 + lc), 16, 0, 0);
    }
    __syncthreads();
#pragma unroll
    for (int kk = 0; kk < 2; ++kk) {
      s8v af[4], bf[4];
#pragma unroll
      for (int i = 0; i < 4; ++i) {
        af[i] = *(const s8v*)(As + (wm * 64 + i * 16 + l15) * 64 + kk * 32 + quad * 8);
        bf[i] = *(const s8v*)(Bs + (wn * 64 + i * 16 + l15) * 64 + kk * 32 + quad * 8);
      }
#pragma unroll
      for (int mi = 0; mi < 4; ++mi)
#pragma unroll
        for (int ni = 0; ni < 4; ++ni)
          acc[mi][ni] = __builtin_amdgcn_mfma_f32_16x16x32_bf16(af[mi], bf[ni],
                                                               acc[mi][ni], 0, 0, 0);
    }
  }
}

// ---------------- fused Q + KV projection GEMM -------------------------------
__global__ __launch_bounds__(256, 3) void gemm_qkv(
    const unsigned short* __restrict__ xb, const unsigned short* __restrict__ ab,
    const unsigned short* __restrict__ wq, const unsigned short* __restrict__ wkv,
    const float* __restrict__ q_b, const float* __restrict__ kv_b,
    unsigned short* __restrict__ Qs, unsigned short* __restrict__ Kb,
    unsigned short* __restrict__ Vb) {
  __shared__ __align__(16) unsigned short As[128 * 64];
  __shared__ __align__(16) unsigned short Bs[128 * 64];
  const int tid = threadIdx.x;
  const int lane = tid & 63, wave = tid >> 6;
  const int wm = wave & 1, wn = wave >> 1;
  const int l15 = lane & 15, quad = lane >> 4;
  const int row0 = blockIdx.x * 128;
  const int y = blockIdx.y;
  const bool isQ = (y < 6);
  const int col0 = (isQ ? y : y - 6) * 128;
  const unsigned short* A = isQ ? xb : ab;
  const unsigned short* W = isQ ? wq : wkv;
  const float* bias = isQ ? q_b : kv_b;

  f4v acc[4][4] = {};
  gemm_mainloop(A, W, 768, row0, col0, As, Bs, acc);

#pragma unroll
  for (int mi = 0; mi < 4; ++mi) {
    int rowg = row0 + wm * 64 + mi * 16 + quad * 4;
#pragma unroll
    for (int ni = 0; ni < 4; ++ni) {
      int colg = col0 + wn * 64 + ni * 16 + l15;
      float bv = bias[colg];
      if (!isQ && colg >= 768) {
        int oo = colg - 768;
        int h = oo >> 6, hd = oo & 63;
        int b = rowg / LK, l0 = rowg - b * LK;   // rowg%4==0, no b-crossing
        ushort4 pk;
        pk.x = f2bf(acc[mi][ni][0] + bv);
        pk.y = f2bf(acc[mi][ni][1] + bv);
        pk.z = f2bf(acc[mi][ni][2] + bv);
        pk.w = f2bf(acc[mi][ni][3] + bv);
        *(ushort4*)(Vb + ((((size_t)b * NH + h) * 392 + (l0 >> 2)) * 64 + hd) * 4) = pk;
        continue;
      }
#pragma unroll
      for (int r = 0; r < 4; ++r) {
        float v = acc[mi][ni][r] + bv;
        int row = rowg + r;
        int b = row / LQ, l = row - b * LQ;
        int h = colg >> 6, hd = colg & 63;
        if (isQ) {
          v *= 0.18033688011112042f;   // 0.125 * log2(e) for exp2 softmax
          Qs[(((size_t)b * NH + h) * LQ + l) * 64 + hd] = f2bf(v);
        } else {
          Kb[(((size_t)b * NH + h) * LK + l) * 64 + hd] = f2bf(v);
        }
      }
    }
  }
}

// ---------------- output projection GEMM (fp32 out) --------------------------
__global__ __launch_bounds__(256, 3) void gemm_proj(
    const unsigned short* __restrict__ A, const unsigned short* __restrict__ W,
    const float* __restrict__ bias, float* __restrict__ out) {
  __shared__ __align__(16) unsigned short As[128 * 64];
  __shared__ __align__(16) unsigned short Bs[128 * 64];
  const int tid = threadIdx.x;
  const int lane = tid & 63, wave = tid >> 6;
  const int wm = wave & 1, wn = wave >> 1;
  const int l15 = lane & 15, quad = lane >> 4;
  const int row0 = blockIdx.x * 128;
  const int col0 = blockIdx.y * 128;

  f4v acc[4][4] = {};
  gemm_mainloop(A, W, 768, row0, col0, As, Bs, acc);

#pragma unroll
  for (int mi = 0; mi < 4; ++mi) {
    int rowg = row0 + wm * 64 + mi * 16 + quad * 4;
#pragma unroll
    for (int ni = 0; ni < 4; ++ni) {
      int colg = col0 + wn * 64 + ni * 16 + l15;
      float bv = bias[colg];
#pragma unroll
      for (int r = 0; r < 4; ++r)
        out[(size_t)(rowg + r) * 768 + colg] = acc[mi][ni][r] + bv;
    }
  }
}

// ---------------- flash attention, split-K over 2 halves ---------------------
// grid (13, 48, 2). Each block: 128 q-rows, 7 K-tiles of 112 keys.
// No running max -> partials combine exactly: O = (O0+O1)/(l0+l1).
// Op[half][bh][LQP][64] bf16 unnormalized, Lp[half][bh][LQP] fp32.
__global__ __launch_bounds__(256, 4) void attn(
    const unsigned short* __restrict__ Q, const unsigned short* __restrict__ Kg,
    const unsigned short* __restrict__ Vsw,
    unsigned short* __restrict__ Op, float* __restrict__ Lp) {
  __shared__ __align__(16) unsigned short Kl[112 * 72];
  __shared__ __align__(16) unsigned short Vl[112 * 64];
  const int tid = threadIdx.x;
  const int lane = tid & 63, wave = tid >> 6;
  const int l15 = lane & 15, quad = lane >> 4;
  const int bh = blockIdx.y;
  const int q0 = blockIdx.x * 128;
  const int half = blockIdx.z;
  const int kbeg = half * 784;           // 7 tiles * 112
  const size_t base = (size_t)bh * LK * 64;

  s8v qf[2][2];
#pragma unroll
  for (int mt = 0; mt < 2; ++mt)
#pragma unroll
    for (int kk = 0; kk < 2; ++kk) {
      int row = q0 + wave * 32 + mt * 16 + l15;
      if (row > LQ - 1) row = LQ - 1;
      qf[mt][kk] = *(const s8v*)(Q + base + (size_t)row * 64 + kk * 32 + quad * 8);
    }

  f4v of[2][4] = {};
  float lr[2] = {0.0f, 0.0f};

  for (int kt = 0; kt < 7; ++kt) {
    int k0 = kbeg + kt * 112;
    __syncthreads();
    for (int c = tid; c < 896; c += 256) {   // K tile: 112 x 64, stride 72 (VGPR path)
      int r = c >> 3, kc = c & 7;
      *(uint4*)(Kl + r * 72 + kc * 8) =
          *(const uint4*)(Kg + base + (size_t)(k0 + r) * 64 + kc * 8);
    }
    // V tile: contiguous, lane-linear -> async direct-to-LDS
    for (int c = tid; c < 896; c += 256)
      __builtin_amdgcn_global_load_lds(
          (const __attribute__((address_space(1))) unsigned int*)(Vsw + base + (size_t)k0 * 64 + c * 8),
          (__attribute__((address_space(3))) unsigned int*)(Vl + c * 8), 16, 0, 0);
    __syncthreads();

#pragma unroll
    for (int nt = 0; nt < 7; ++nt) {
      s8v kf0 = *(const s8v*)(Kl + (nt * 16 + l15) * 72 + quad * 8);
      s8v kf1 = *(const s8v*)(Kl + (nt * 16 + l15) * 72 + 32 + quad * 8);
      s4v pf[2];
#pragma unroll
      for (int mt = 0; mt < 2; ++mt) {
        f4v s = {};
        s = __builtin_amdgcn_mfma_f32_16x16x32_bf16(kf0, qf[mt][0], s, 0, 0, 0);
        s = __builtin_amdgcn_mfma_f32_16x16x32_bf16(kf1, qf[mt][1], s, 0, 0, 0);
        float p0 = __builtin_amdgcn_exp2f(s[0]);
        float p1 = __builtin_amdgcn_exp2f(s[1]);
        float p2 = __builtin_amdgcn_exp2f(s[2]);
        float p3 = __builtin_amdgcn_exp2f(s[3]);
        lr[mt] += (p0 + p1) + (p2 + p3);
        union { float f; unsigned u; } a0, a1, a2, a3;
        a0.f = p0; a1.f = p1; a2.f = p2; a3.f = p3;
        union { uint2 u; s4v s; } pk;
        pk.u.x = __builtin_amdgcn_perm(a1.u, a0.u, 0x07060302u);
        pk.u.y = __builtin_amdgcn_perm(a3.u, a2.u, 0x07060302u);
        pf[mt] = pk.s;
      }
#pragma unroll
      for (int nd = 0; nd < 4; ++nd) {
        s4v vf = *(const s4v*)(Vl + ((nt * 4 + quad) << 8) + ((nd * 16 + l15) << 2));
        of[0][nd] = __builtin_amdgcn_mfma_f32_16x16x16bf16_1k(pf[0], vf, of[0][nd], 0, 0, 0);
        of[1][nd] = __builtin_amdgcn_mfma_f32_16x16x16bf16_1k(pf[1], vf, of[1][nd], 0, 0, 0);
      }
    }
  }

#pragma unroll
  for (int mt = 0; mt < 2; ++mt) {
    lr[mt] += __shfl_xor(lr[mt], 16);
    lr[mt] += __shfl_xor(lr[mt], 32);
  }

  // partial store (unnormalized O in bf16, l in fp32); padded rows harmless
  const size_t obase = ((size_t)(half * 48 + bh) * LQP + q0);
#pragma unroll
  for (int mt = 0; mt < 2; ++mt) {
#pragma unroll
    for (int r = 0; r < 4; ++r) {
      int rowl = wave * 32 + mt * 16 + quad * 4 + r;
#pragma unroll
      for (int nd = 0; nd < 4; ++nd)
        Op[(obase + rowl) * 64 + nd * 16 + l15] = f2bf(of[mt][nd][r]);
    }
    if (quad == 0)
      Lp[obase + wave * 32 + mt * 16 + l15] = lr[mt];
  }
}

// ---------------- split-K merge: O = (O0+O1)/(l0+l1), write [b,l,h*64+hd] ----
__global__ void attn_merge(const unsigned short* __restrict__ Op,
                           const float* __restrict__ Lp,
                           unsigned short* __restrict__ Om) {
  int i = blockIdx.x * 256 + threadIdx.x;
  if (i >= 48 * LQ * 8) return;
  int hd8 = (i & 7) * 8;
  int t = i >> 3;
  int row = t % LQ;
  int bh = t / LQ;
  int b = bh / NH, h = bh - b * NH;
  const unsigned short* p0 = Op + ((size_t)bh * LQP + row) * 64 + hd8;
  const unsigned short* p1 = Op + ((size_t)(48 + bh) * LQP + row) * 64 + hd8;
  float inv = 1.0f / (Lp[(size_t)bh * LQP + row] + Lp[(size_t)(48 + bh) * LQP + row]);
  ushort4 a0 = *(const ushort4*)p0, a1 = *(const ushort4*)(p0 + 4);
  ushort4 b0 = *(const ushort4*)p1, b1 = *(const ushort4*)(p1 + 4);
  ushort4 o0, o1;
  o0.x = f2bf((bf2f(a0.x) + bf2f(b0.x)) * inv);
  o0.y = f2bf((bf2f(a0.y) + bf2f(b0.y)) * inv);
  o0.z = f2bf((bf2f(a0.z) + bf2f(b0.z)) * inv);
  o0.w = f2bf((bf2f(a0.w) + bf2f(b0.w)) * inv);
  o1.x = f2bf((bf2f(a1.x) + bf2f(b1.x)) * inv);
  o1.y = f2bf((bf2f(a1.y) + bf2f(b1.y)) * inv);
  o1.z = f2bf((bf2f(a1.z) + bf2f(b1.z)) * inv);
  o1.w = f2bf((bf2f(a1.w) + bf2f(b1.w)) * inv);
  unsigned short* dst = Om + ((size_t)(b * LQ) + row) * 768 + h * 64 + hd8;
  *(ushort4*)dst = o0;
  *(ushort4*)(dst + 4) = o1;
}

// ---------------- launcher ----------------
extern "C" void kernel_launch(void* const* d_in, const int* in_sizes, int n_in,
                              void* d_out, int out_size, void* d_ws, size_t ws_size,
                              hipStream_t stream) {
  const float* t_x    = (const float*)d_in[0];
  const float* audio  = (const float*)d_in[1];
  const float* sp     = (const float*)d_in[2];
  const float* asp    = (const float*)d_in[3];
  const float* tp     = (const float*)d_in[4];
  const float* atp    = (const float*)d_in[5];
  const float* q_w    = (const float*)d_in[6];
  const float* q_b    = (const float*)d_in[7];
  const float* kv_w   = (const float*)d_in[8];
  const float* kv_b   = (const float*)d_in[9];
  const float* proj_w = (const float*)d_in[10];
  const float* proj_b = (const float*)d_in[11];
  float* out = (float*)d_out;

  char* ws = (char*)d_ws;
  size_t off = 0;
  auto alloc = [&](size_t bytes) -> void* {
    void* p = ws + off;
    off += (bytes + 255) & ~(size_t)255;
    return p;
  };
  const size_t TOK = 6272;  // B*1568
  unsigned short* xb  = (unsigned short*)alloc(TOK * 768 * 2);
  unsigned short* ab  = (unsigned short*)alloc(TOK * 768 * 2);
  unsigned short* wq  = (unsigned short*)alloc(768 * 768 * 2);
  unsigned short* wkv = (unsigned short*)alloc(1536 * 768 * 2);
  unsigned short* wp  = (unsigned short*)alloc(768 * 768 * 2);
  unsigned short* Qs  = (unsigned short*)alloc(TOK * 768 * 2);  // [B,H,Lq,64] scaled
  unsigned short* Kb  = (unsigned short*)alloc(TOK * 768 * 2);  // [B,H,Lk,64]
  unsigned short* Vb  = (unsigned short*)alloc(TOK * 768 * 2);  // [B,H,Lk/4,64,4] swizzled

  // attn partials overlay the xb..wkv region (dead during attn):
  //   Op: 2*48*1664*64 bf16 = 20,447,232 B  at ws+0
  //   Lp: 2*48*1664 fp32    =    638,976 B  at ws+20,447,232  (ends < wp offset)
  unsigned short* Op = (unsigned short*)ws;
  float*          Lp = (float*)(ws + (size_t)2 * 48 * LQP * 64 * 2);
  unsigned short* Om = Qs;   // merged O reuses dead Qs region

  dim3 blk(256);
  const int n1 = 768 * 768 / 4, n2 = 1536 * 768 / 4;
  int total4 = (int)(TOK * 192);
  int nprep = 2 * n1 + n2 + 2 * total4;
  prep_all<<<dim3((nprep + 255) / 256), blk, 0, stream>>>(
      t_x, audio, sp, asp, tp, atp, q_w, kv_w, proj_w, xb, ab, wq, wkv, wp, total4);

  gemm_qkv<<<dim3(49, 18), blk, 0, stream>>>(xb, ab, wq, wkv, q_b, kv_b, Qs, Kb, Vb);

  attn<<<dim3(13, 48, 2), blk, 0, stream>>>(Qs, Kb, Vb, Op, Lp);

  attn_merge<<<dim3((48 * LQ * 8 + 255) / 256), blk, 0, stream>>>(Op, Lp, Om);

  gemm_proj<<<dim3(49, 6), blk, 0, stream>>>(Om, wp, proj_b, out);
}

// Round 6
// 236.340 us; speedup vs baseline: 1.4947x; 1.0191x over previous
//
#include <hip/hip_runtime.h>

typedef short s8v __attribute__((ext_vector_type(8)));
typedef short s4v __attribute__((ext_vector_type(4)));
typedef float f4v __attribute__((ext_vector_type(4)));

#define LQ 1568
#define LK 1568
#define NH 12
#define LQP 1664   // 13*128 padded q-rows per head

__device__ __forceinline__ unsigned short f2bf(float f) {
  union { float f; unsigned u; } x; x.f = f;
  unsigned r = x.u + 0x7FFFu + ((x.u >> 16) & 1u);
  return (unsigned short)(r >> 16);
}
__device__ __forceinline__ float bf2f(unsigned short s) {
  union { unsigned u; float f; } x; x.u = ((unsigned)s) << 16;
  return x.f;
}

// ---------------- prep: weights->bf16 + pos-embed adds, one launch ----------
__global__ void prep_all(const float* __restrict__ t_x, const float* __restrict__ audio,
                         const float* __restrict__ sp, const float* __restrict__ asp,
                         const float* __restrict__ tp, const float* __restrict__ atp,
                         const float* __restrict__ q_w, const float* __restrict__ kv_w,
                         const float* __restrict__ proj_w,
                         unsigned short* __restrict__ xb, unsigned short* __restrict__ ab,
                         unsigned short* __restrict__ wq, unsigned short* __restrict__ wkv,
                         unsigned short* __restrict__ wp, int total4) {
  const int n1 = 768 * 768 / 4, n2 = 1536 * 768 / 4;
  const int nconv = 2 * n1 + n2;
  int i = blockIdx.x * 256 + threadIdx.x;
  if (i < nconv) {
    const float* src; unsigned short* dst; int j = i;
    if (i < n1)           { src = q_w;    dst = wq;  }
    else if (i < n1 + n2) { src = kv_w;   dst = wkv; j = i - n1; }
    else                  { src = proj_w; dst = wp;  j = i - n1 - n2; }
    float4 v = *(const float4*)(src + (size_t)j * 4);
    ushort4 o;
    o.x = f2bf(v.x); o.y = f2bf(v.y); o.z = f2bf(v.z); o.w = f2bf(v.w);
    *(ushort4*)(dst + (size_t)j * 4) = o;
    return;
  }
  i -= nconv;
  if (i >= 2 * total4) return;
  if (i < total4) {
    int d4 = (i % 192) * 4;
    int row = i / 192;            // b*1568 + l
    int l = row % LQ;
    int t = l / 196, n = l % 196;
    float4 a  = *(const float4*)(t_x + (size_t)i * 4);
    float4 s  = *(const float4*)(sp + n * 768 + d4);
    float4 tt = *(const float4*)(tp + t * 768 + d4);
    ushort4 o;
    o.x = f2bf(a.x + s.x + tt.x);
    o.y = f2bf(a.y + s.y + tt.y);
    o.z = f2bf(a.z + s.z + tt.z);
    o.w = f2bf(a.w + s.w + tt.w);
    *(ushort4*)(xb + (size_t)i * 4) = o;
  } else {
    i -= total4;
    int d4 = (i % 192) * 4;
    int row = i / 192;            // b*1568 + (na*8+ta)
    int b = row / LK;
    int r2 = row % LK;
    int na = r2 >> 3, ta = r2 & 7;
    const float* src = audio + ((size_t)(2 + na) * 32 + b * 8 + ta) * 768 + d4;
    float4 a  = *(const float4*)src;
    float4 s  = *(const float4*)(asp + na * 768 + d4);
    float4 tt = *(const float4*)(atp + ta * 768 + d4);
    ushort4 o;
    o.x = f2bf(a.x + s.x + tt.x);
    o.y = f2bf(a.y + s.y + tt.y);
    o.z = f2bf(a.z + s.z + tt.z);
    o.w = f2bf(a.w + s.w + tt.w);
    *(ushort4*)(ab + (size_t)i * 4) = o;
  }
}

// ---------------- shared GEMM mainloop: m97 structure ------------------------
__device__ __forceinline__ void gemm_mainloop(
    const unsigned short* __restrict__ A, const unsigned short* __restrict__ W,
    int K, int row0, int col0,
    unsigned short* As, unsigned short* Bs, f4v acc[4][4]) {
  const int tid = threadIdx.x;
  const int lane = tid & 63, wave = tid >> 6;
  const int wm = wave & 1, wn = wave >> 1;
  const int l15 = lane & 15, quad = lane >> 4;
  const int lr = tid >> 3, lc = (tid & 7) * 8;   // flat LDS offset = tid*8 elems

  for (int k0 = 0; k0 < K; k0 += 64) {
    __syncthreads();
#pragma unroll
    for (int it = 0; it < 4; ++it) {
      int row = lr + it * 32;
      __builtin_amdgcn_global_load_lds(
          (const __attribute__((address_space(1))) unsigned int*)(A + (size_t)(row0 + row) * K + k0 + lc),
          (__attribute__((address_space(3))) unsigned int*)(As + row * 64 + lc), 16, 0, 0);
      __builtin_amdgcn_global_load_lds(
          (const __attribute__((address_space(1))) unsigned int*)(W + (size_t)(col0 + row) * K + k0 + lc),
          (__attribute__((address_space(3))) unsigned int*)(Bs + row * 64 + lc), 16, 0, 0);
    }
    __syncthreads();
#pragma unroll
    for (int kk = 0; kk < 2; ++kk) {
      s8v af[4], bf[4];
#pragma unroll
      for (int i = 0; i < 4; ++i) {
        af[i] = *(const s8v*)(As + (wm * 64 + i * 16 + l15) * 64 + kk * 32 + quad * 8);
        bf[i] = *(const s8v*)(Bs + (wn * 64 + i * 16 + l15) * 64 + kk * 32 + quad * 8);
      }
#pragma unroll
      for (int mi = 0; mi < 4; ++mi)
#pragma unroll
        for (int ni = 0; ni < 4; ++ni)
          acc[mi][ni] = __builtin_amdgcn_mfma_f32_16x16x32_bf16(af[mi], bf[ni],
                                                               acc[mi][ni], 0, 0, 0);
    }
  }
}

// ---------------- fused Q + KV projection GEMM -------------------------------
// K output is written in the attn-LDS image: per (bh, tile) 112x72 padded tiles
// so attn can stage K with lane-linear global_load_lds.
__global__ __launch_bounds__(256, 4) void gemm_qkv(
    const unsigned short* __restrict__ xb, const unsigned short* __restrict__ ab,
    const unsigned short* __restrict__ wq, const unsigned short* __restrict__ wkv,
    const float* __restrict__ q_b, const float* __restrict__ kv_b,
    unsigned short* __restrict__ Qs, unsigned short* __restrict__ Kb,
    unsigned short* __restrict__ Vb) {
  __shared__ __align__(16) unsigned short As[128 * 64];
  __shared__ __align__(16) unsigned short Bs[128 * 64];
  const int tid = threadIdx.x;
  const int lane = tid & 63, wave = tid >> 6;
  const int wm = wave & 1, wn = wave >> 1;
  const int l15 = lane & 15, quad = lane >> 4;
  const int row0 = blockIdx.x * 128;
  const int y = blockIdx.y;
  const bool isQ = (y < 6);
  const int col0 = (isQ ? y : y - 6) * 128;
  const unsigned short* A = isQ ? xb : ab;
  const unsigned short* W = isQ ? wq : wkv;
  const float* bias = isQ ? q_b : kv_b;

  f4v acc[4][4] = {};
  gemm_mainloop(A, W, 768, row0, col0, As, Bs, acc);

#pragma unroll
  for (int mi = 0; mi < 4; ++mi) {
    int rowg = row0 + wm * 64 + mi * 16 + quad * 4;
#pragma unroll
    for (int ni = 0; ni < 4; ++ni) {
      int colg = col0 + wn * 64 + ni * 16 + l15;
      float bv = bias[colg];
      if (!isQ && colg >= 768) {
        int oo = colg - 768;
        int h = oo >> 6, hd = oo & 63;
        int b = rowg / LK, l0 = rowg - b * LK;   // rowg%4==0, no b-crossing
        ushort4 pk;
        pk.x = f2bf(acc[mi][ni][0] + bv);
        pk.y = f2bf(acc[mi][ni][1] + bv);
        pk.z = f2bf(acc[mi][ni][2] + bv);
        pk.w = f2bf(acc[mi][ni][3] + bv);
        *(ushort4*)(Vb + ((((size_t)b * NH + h) * 392 + (l0 >> 2)) * 64 + hd) * 4) = pk;
        continue;
      }
#pragma unroll
      for (int r = 0; r < 4; ++r) {
        float v = acc[mi][ni][r] + bv;
        int row = rowg + r;
        int b = row / LQ, l = row - b * LQ;
        int h = colg >> 6, hd = colg & 63;
        if (isQ) {
          v *= 0.18033688011112042f;   // 0.125 * log2(e) for exp2 softmax
          Qs[(((size_t)b * NH + h) * LQ + l) * 64 + hd] = f2bf(v);
        } else {
          int tile = l / 112, rr = l - tile * 112;
          Kb[(((size_t)b * NH + h) * 14 + tile) * 8064 + rr * 72 + hd] = f2bf(v);
        }
      }
    }
  }
}

// ---------------- output projection GEMM (fp32 out) --------------------------
__global__ __launch_bounds__(256, 4) void gemm_proj(
    const unsigned short* __restrict__ A, const unsigned short* __restrict__ W,
    const float* __restrict__ bias, float* __restrict__ out) {
  __shared__ __align__(16) unsigned short As[128 * 64];
  __shared__ __align__(16) unsigned short Bs[128 * 64];
  const int tid = threadIdx.x;
  const int lane = tid & 63, wave = tid >> 6;
  const int wm = wave & 1, wn = wave >> 1;
  const int l15 = lane & 15, quad = lane >> 4;
  const int row0 = blockIdx.x * 128;
  const int col0 = blockIdx.y * 128;

  f4v acc[4][4] = {};
  gemm_mainloop(A, W, 768, row0, col0, As, Bs, acc);

#pragma unroll
  for (int mi = 0; mi < 4; ++mi) {
    int rowg = row0 + wm * 64 + mi * 16 + quad * 4;
#pragma unroll
    for (int ni = 0; ni < 4; ++ni) {
      int colg = col0 + wn * 64 + ni * 16 + l15;
      float bv = bias[colg];
#pragma unroll
      for (int r = 0; r < 4; ++r)
        out[(size_t)(rowg + r) * 768 + colg] = acc[mi][ni][r] + bv;
    }
  }
}

// ---------------- flash attention, split-K over Z slices ---------------------
// grid (13, 48, Z). Each block: 128 q-rows, tiles [z*14/Z, (z+1)*14/Z) of 112 keys.
// No running max -> partials combine exactly: O = sum(Oz) / sum(lz).
// K staged via global_load_lds from the pre-swizzled 112x72 tile image.
__global__ __launch_bounds__(256, 4) void attn(
    const unsigned short* __restrict__ Q, const unsigned short* __restrict__ Kg,
    const unsigned short* __restrict__ Vsw,
    unsigned short* __restrict__ Op, float* __restrict__ Lp, int Z) {
  __shared__ __align__(16) unsigned short Kl[112 * 72];
  __shared__ __align__(16) unsigned short Vl[112 * 64];
  const int tid = threadIdx.x;
  const int lane = tid & 63, wave = tid >> 6;
  const int l15 = lane & 15, quad = lane >> 4;
  const int bh = blockIdx.y;
  const int q0 = blockIdx.x * 128;
  const int z = blockIdx.z;
  const int t0 = (z * 14) / Z, t1 = ((z + 1) * 14) / Z;
  const size_t base = (size_t)bh * LK * 64;

  s8v qf[2][2];
#pragma unroll
  for (int mt = 0; mt < 2; ++mt)
#pragma unroll
    for (int kk = 0; kk < 2; ++kk) {
      int row = q0 + wave * 32 + mt * 16 + l15;
      if (row > LQ - 1) row = LQ - 1;
      qf[mt][kk] = *(const s8v*)(Q + base + (size_t)row * 64 + kk * 32 + quad * 8);
    }

  f4v of[2][4] = {};
  float lr[2] = {0.0f, 0.0f};

  for (int kt = t0; kt < t1; ++kt) {
    __syncthreads();
    // K tile: contiguous copy of the pre-swizzled 112x72 image (1008 x 16B)
    const unsigned short* Ksrc = Kg + ((size_t)bh * 14 + kt) * 8064;
    for (int c = tid; c < 1008; c += 256)
      __builtin_amdgcn_global_load_lds(
          (const __attribute__((address_space(1))) unsigned int*)(Ksrc + c * 8),
          (__attribute__((address_space(3))) unsigned int*)(Kl + c * 8), 16, 0, 0);
    // V tile: contiguous (896 x 16B)
    const unsigned short* Vsrc = Vsw + base + (size_t)kt * 112 * 64;
    for (int c = tid; c < 896; c += 256)
      __builtin_amdgcn_global_load_lds(
          (const __attribute__((address_space(1))) unsigned int*)(Vsrc + c * 8),
          (__attribute__((address_space(3))) unsigned int*)(Vl + c * 8), 16, 0, 0);
    __syncthreads();

#pragma unroll
    for (int nt = 0; nt < 7; ++nt) {
      s8v kf0 = *(const s8v*)(Kl + (nt * 16 + l15) * 72 + quad * 8);
      s8v kf1 = *(const s8v*)(Kl + (nt * 16 + l15) * 72 + 32 + quad * 8);
      s4v pf[2];
#pragma unroll
      for (int mt = 0; mt < 2; ++mt) {
        f4v s = {};
        s = __builtin_amdgcn_mfma_f32_16x16x32_bf16(kf0, qf[mt][0], s, 0, 0, 0);
        s = __builtin_amdgcn_mfma_f32_16x16x32_bf16(kf1, qf[mt][1], s, 0, 0, 0);
        float p0 = __builtin_amdgcn_exp2f(s[0]);
        float p1 = __builtin_amdgcn_exp2f(s[1]);
        float p2 = __builtin_amdgcn_exp2f(s[2]);
        float p3 = __builtin_amdgcn_exp2f(s[3]);
        lr[mt] += (p0 + p1) + (p2 + p3);
        union { float f; unsigned u; } a0, a1, a2, a3;
        a0.f = p0; a1.f = p1; a2.f = p2; a3.f = p3;
        union { uint2 u; s4v s; } pk;
        pk.u.x = __builtin_amdgcn_perm(a1.u, a0.u, 0x07060302u);
        pk.u.y = __builtin_amdgcn_perm(a3.u, a2.u, 0x07060302u);
        pf[mt] = pk.s;
      }
#pragma unroll
      for (int nd = 0; nd < 4; ++nd) {
        s4v vf = *(const s4v*)(Vl + ((nt * 4 + quad) << 8) + ((nd * 16 + l15) << 2));
        of[0][nd] = __builtin_amdgcn_mfma_f32_16x16x16bf16_1k(pf[0], vf, of[0][nd], 0, 0, 0);
        of[1][nd] = __builtin_amdgcn_mfma_f32_16x16x16bf16_1k(pf[1], vf, of[1][nd], 0, 0, 0);
      }
    }
  }

#pragma unroll
  for (int mt = 0; mt < 2; ++mt) {
    lr[mt] += __shfl_xor(lr[mt], 16);
    lr[mt] += __shfl_xor(lr[mt], 32);
  }

  const size_t obase = ((size_t)(z * 48 + bh) * LQP + q0);
#pragma unroll
  for (int mt = 0; mt < 2; ++mt) {
#pragma unroll
    for (int r = 0; r < 4; ++r) {
      int rowl = wave * 32 + mt * 16 + quad * 4 + r;
#pragma unroll
      for (int nd = 0; nd < 4; ++nd)
        Op[(obase + rowl) * 64 + nd * 16 + l15] = f2bf(of[mt][nd][r]);
    }
    if (quad == 0)
      Lp[obase + wave * 32 + mt * 16 + l15] = lr[mt];
  }
}

// ---------------- split-K merge: O = sum(Oz)/sum(lz), write [b,l,h*64+hd] ----
__global__ void attn_merge(const unsigned short* __restrict__ Op,
                           const float* __restrict__ Lp,
                           unsigned short* __restrict__ Om, int Z) {
  int i = blockIdx.x * 256 + threadIdx.x;
  if (i >= 48 * LQ * 8) return;
  int hd8 = (i & 7) * 8;
  int t = i >> 3;
  int row = t % LQ;
  int bh = t / LQ;
  int b = bh / NH, h = bh - b * NH;
  float acc[8] = {};
  float lsum = 0.0f;
  for (int z = 0; z < Z; ++z) {
    size_t rb = (size_t)(z * 48 + bh) * LQP + row;
    lsum += Lp[rb];
    const unsigned short* p = Op + rb * 64 + hd8;
    ushort4 a0 = *(const ushort4*)p, a1 = *(const ushort4*)(p + 4);
    acc[0] += bf2f(a0.x); acc[1] += bf2f(a0.y); acc[2] += bf2f(a0.z); acc[3] += bf2f(a0.w);
    acc[4] += bf2f(a1.x); acc[5] += bf2f(a1.y); acc[6] += bf2f(a1.z); acc[7] += bf2f(a1.w);
  }
  float inv = 1.0f / lsum;
  ushort4 o0, o1;
  o0.x = f2bf(acc[0] * inv); o0.y = f2bf(acc[1] * inv);
  o0.z = f2bf(acc[2] * inv); o0.w = f2bf(acc[3] * inv);
  o1.x = f2bf(acc[4] * inv); o1.y = f2bf(acc[5] * inv);
  o1.z = f2bf(acc[6] * inv); o1.w = f2bf(acc[7] * inv);
  unsigned short* dst = Om + ((size_t)(b * LQ) + row) * 768 + h * 64 + hd8;
  *(ushort4*)dst = o0;
  *(ushort4*)(dst + 4) = o1;
}

// ---------------- launcher ----------------
extern "C" void kernel_launch(void* const* d_in, const int* in_sizes, int n_in,
                              void* d_out, int out_size, void* d_ws, size_t ws_size,
                              hipStream_t stream) {
  const float* t_x    = (const float*)d_in[0];
  const float* audio  = (const float*)d_in[1];
  const float* sp     = (const float*)d_in[2];
  const float* asp    = (const float*)d_in[3];
  const float* tp     = (const float*)d_in[4];
  const float* atp    = (const float*)d_in[5];
  const float* q_w    = (const float*)d_in[6];
  const float* q_b    = (const float*)d_in[7];
  const float* kv_w   = (const float*)d_in[8];
  const float* kv_b   = (const float*)d_in[9];
  const float* proj_w = (const float*)d_in[10];
  const float* proj_b = (const float*)d_in[11];
  float* out = (float*)d_out;

  char* ws = (char*)d_ws;
  size_t off = 0;
  auto alloc = [&](size_t bytes) -> void* {
    void* p = ws + off;
    off += (bytes + 255) & ~(size_t)255;
    return p;
  };
  const size_t TOK = 6272;  // B*1568
  unsigned short* xb  = (unsigned short*)alloc(TOK * 768 * 2);
  unsigned short* ab  = (unsigned short*)alloc(TOK * 768 * 2);
  unsigned short* wq  = (unsigned short*)alloc(768 * 768 * 2);
  unsigned short* wkv = (unsigned short*)alloc(1536 * 768 * 2);
  unsigned short* wp  = (unsigned short*)alloc(768 * 768 * 2);
  unsigned short* Qs  = (unsigned short*)alloc(TOK * 768 * 2);        // [B,H,Lq,64] scaled
  unsigned short* Kb  = (unsigned short*)alloc((size_t)48 * 14 * 8064 * 2);  // swizzled tiles
  unsigned short* Vb  = (unsigned short*)alloc(TOK * 768 * 2);        // [B,H,Lk/4,64,4]

  // split-K partial buffers: prefer fresh region (Z=7/4), fallback overlay (Z=2)
  auto need = [&](int Z) {
    return off + (size_t)Z * 48 * LQP * 64 * 2 + (size_t)Z * 48 * LQP * 4 + 512;
  };
  int Z;
  unsigned short* Op;
  float* Lp;
  if (ws_size >= need(7)) {
    Z = 7;
    Op = (unsigned short*)alloc((size_t)7 * 48 * LQP * 64 * 2);
    Lp = (float*)alloc((size_t)7 * 48 * LQP * 4);
  } else if (ws_size >= need(4)) {
    Z = 4;
    Op = (unsigned short*)alloc((size_t)4 * 48 * LQP * 64 * 2);
    Lp = (float*)alloc((size_t)4 * 48 * LQP * 4);
  } else {
    Z = 2;   // overlay dead xb..wkv region (21.1 MB <= 22.8 MB)
    Op = (unsigned short*)ws;
    Lp = (float*)(ws + (size_t)2 * 48 * LQP * 64 * 2);
  }
  unsigned short* Om = Qs;   // merged O reuses dead Qs region

  dim3 blk(256);
  const int n1 = 768 * 768 / 4, n2 = 1536 * 768 / 4;
  int total4 = (int)(TOK * 192);
  int nprep = 2 * n1 + n2 + 2 * total4;
  prep_all<<<dim3((nprep + 255) / 256), blk, 0, stream>>>(
      t_x, audio, sp, asp, tp, atp, q_w, kv_w, proj_w, xb, ab, wq, wkv, wp, total4);

  gemm_qkv<<<dim3(49, 18), blk, 0, stream>>>(xb, ab, wq, wkv, q_b, kv_b, Qs, Kb, Vb);

  attn<<<dim3(13, 48, Z), blk, 0, stream>>>(Qs, Kb, Vb, Op, Lp, Z);

  attn_merge<<<dim3((48 * LQ * 8 + 255) / 256), blk, 0, stream>>>(Op, Lp, Om, Z);

  gemm_proj<<<dim3(49, 6), blk, 0, stream>>>(Om, wp, proj_b, out);
}